// Round 1
// baseline (815.684 us; speedup 1.0000x reference)
//
#include <hip/hip_runtime.h>
#include <hip/hip_bf16.h>

#define N_NODES   50000
#define N_EDGES   640000
#define NODE_DIM  16
#define HIDDEN    128
#define LATENT    64
#define MAX_NODES 100
#define NUM_GRAPHS 256

// ---------------------------------------------------------------------------
// Edge scatter-add: agg[dst[e]][d] += x[src[e]][d]   (agg pre-initialized = x)
// ---------------------------------------------------------------------------
template <int DIM>
__global__ void scatter_add_kernel(const float* __restrict__ x,
                                   const int* __restrict__ src,
                                   const int* __restrict__ dst,
                                   float* __restrict__ agg) {
    const long total = (long)N_EDGES * DIM;
    for (long i = blockIdx.x * (long)blockDim.x + threadIdx.x; i < total;
         i += (long)gridDim.x * blockDim.x) {
        const int e = (int)(i / DIM);
        const int d = (int)(i - (long)e * DIM);
        atomicAdd(&agg[(long)dst[e] * DIM + d], x[(long)src[e] * DIM + d]);
    }
}

// ---------------------------------------------------------------------------
// GIN MLP: out = relu( relu(in @ wa + ba) @ wb + bb ),  in: N_NODES x K0
// NB nodes per block, 128 threads (one per output dim), weights read once
// per block via register accumulators.
// ---------------------------------------------------------------------------
template <int K0, int NB>
__global__ void gin_mlp_kernel(const float* __restrict__ in,
                               const float* __restrict__ wa, const float* __restrict__ ba,
                               const float* __restrict__ wb, const float* __restrict__ bb,
                               float* __restrict__ out) {
    __shared__ float s_in[NB][K0];
    __shared__ float s_mid[NB][HIDDEN];
    const int d  = threadIdx.x;          // 0..127
    const int n0 = blockIdx.x * NB;

    for (int idx = threadIdx.x; idx < NB * K0; idx += blockDim.x) {
        const int i = idx / K0;
        const int k = idx - i * K0;
        const int n = n0 + i;
        s_in[i][k] = (n < N_NODES) ? in[(long)n * K0 + k] : 0.f;
    }
    __syncthreads();

    float acc[NB];
    {
        const float bias = ba[d];
        #pragma unroll
        for (int i = 0; i < NB; ++i) acc[i] = bias;
        for (int k = 0; k < K0; ++k) {
            const float w = wa[k * HIDDEN + d];
            #pragma unroll
            for (int i = 0; i < NB; ++i) acc[i] += s_in[i][k] * w;
        }
        #pragma unroll
        for (int i = 0; i < NB; ++i) s_mid[i][d] = fmaxf(acc[i], 0.f);
    }
    __syncthreads();
    {
        const float bias = bb[d];
        #pragma unroll
        for (int i = 0; i < NB; ++i) acc[i] = bias;
        for (int k = 0; k < HIDDEN; ++k) {
            const float w = wb[k * HIDDEN + d];
            #pragma unroll
            for (int i = 0; i < NB; ++i) acc[i] += s_mid[i][k] * w;
        }
        #pragma unroll
        for (int i = 0; i < NB; ++i) {
            const int n = n0 + i;
            if (n < N_NODES) out[(long)n * HIDDEN + d] = fmaxf(acc[i], 0.f);
        }
    }
}

// ---------------------------------------------------------------------------
// Mean pooling over sorted batch ids: run-length accumulate, few atomics.
// 128 threads (one per hidden dim), 128 nodes per block.
// ---------------------------------------------------------------------------
__global__ void pool_kernel(const float* __restrict__ h,
                            const int* __restrict__ batch,
                            float* __restrict__ summed,   // NUM_GRAPHS x HIDDEN
                            float* __restrict__ counts) { // NUM_GRAPHS
    const int NPB = 128;
    const int n0 = blockIdx.x * NPB;
    if (n0 >= N_NODES) return;
    const int nend = min(n0 + NPB, N_NODES);
    const int d = threadIdx.x;

    int cur = batch[n0];
    float acc = 0.f;
    int cnt = 0;
    for (int n = n0; n < nend; ++n) {
        const int g = batch[n];
        if (g != cur) {
            atomicAdd(&summed[cur * HIDDEN + d], acc);
            if (d == 0) atomicAdd(&counts[cur], (float)cnt);
            acc = 0.f; cnt = 0; cur = g;
        }
        acc += h[(long)n * HIDDEN + d];
        ++cnt;
    }
    atomicAdd(&summed[cur * HIDDEN + d], acc);
    if (d == 0) atomicAdd(&counts[cur], (float)cnt);
}

// ---------------------------------------------------------------------------
// Per-graph head: pooled -> mu, logvar, z -> hd (decoder trunk).
// One block per graph, 128 threads.
// ---------------------------------------------------------------------------
__global__ void head_kernel(const float* __restrict__ summed,
                            const float* __restrict__ counts,
                            const float* __restrict__ eps,
                            const float* __restrict__ wmu, const float* __restrict__ bmu,
                            const float* __restrict__ wlv, const float* __restrict__ blv,
                            const float* __restrict__ wd1, const float* __restrict__ bd1,
                            const float* __restrict__ wd2, const float* __restrict__ bd2,
                            float* __restrict__ out_mu, float* __restrict__ out_lv,
                            float* __restrict__ hd) {
    const int g = blockIdx.x;
    const int d = threadIdx.x;
    __shared__ float s_pool[HIDDEN];
    __shared__ float s_z[LATENT];
    __shared__ float s_h1[HIDDEN];

    const float cnt = fmaxf(counts[g], 1.f);
    s_pool[d] = summed[g * HIDDEN + d] / cnt;
    __syncthreads();

    if (d < LATENT) {
        float m = bmu[d], lv = blv[d];
        for (int k = 0; k < HIDDEN; ++k) {
            const float p = s_pool[k];
            m  += p * wmu[k * LATENT + d];
            lv += p * wlv[k * LATENT + d];
        }
        lv = fminf(fmaxf(lv, -5.f), 5.f);
        out_mu[g * LATENT + d] = m;
        out_lv[g * LATENT + d] = lv;
        s_z[d] = m + eps[g * LATENT + d] * expf(0.5f * lv);
    }
    __syncthreads();
    {
        float a = bd1[d];
        for (int k = 0; k < LATENT; ++k) a += s_z[k] * wd1[k * HIDDEN + d];
        s_h1[d] = fmaxf(a, 0.f);
    }
    __syncthreads();
    {
        float a = bd2[d];
        for (int k = 0; k < HIDDEN; ++k) a += s_h1[k] * wd2[k * HIDDEN + d];
        hd[g * HIDDEN + d] = a;
    }
}

// ---------------------------------------------------------------------------
// node_features = softmax((hd @ wn + bn).reshape(G,100,16), axis=-1)
// One block per graph, 128 threads.
// ---------------------------------------------------------------------------
__global__ void nodefeat_kernel(const float* __restrict__ hd,
                                const float* __restrict__ wn, const float* __restrict__ bn,
                                float* __restrict__ out_nf) {
    const int g = blockIdx.x;
    const int tid = threadIdx.x;
    __shared__ float s_hd[HIDDEN];
    __shared__ float s_logit[MAX_NODES * NODE_DIM];  // 1600

    if (tid < HIDDEN) s_hd[tid] = hd[g * HIDDEN + tid];
    __syncthreads();

    for (int o = tid; o < MAX_NODES * NODE_DIM; o += blockDim.x) {
        float a = bn[o];
        for (int k = 0; k < HIDDEN; ++k) a += s_hd[k] * wn[k * (MAX_NODES * NODE_DIM) + o];
        s_logit[o] = a;
    }
    __syncthreads();

    for (int m = tid; m < MAX_NODES; m += blockDim.x) {
        float mx = -1e30f;
        #pragma unroll
        for (int d = 0; d < NODE_DIM; ++d) mx = fmaxf(mx, s_logit[m * NODE_DIM + d]);
        float e[NODE_DIM];
        float sum = 0.f;
        #pragma unroll
        for (int d = 0; d < NODE_DIM; ++d) {
            e[d] = expf(s_logit[m * NODE_DIM + d] - mx);
            sum += e[d];
        }
        const float inv = 1.f / sum;
        #pragma unroll
        for (int d = 0; d < NODE_DIM; ++d)
            out_nf[(long)g * MAX_NODES * NODE_DIM + m * NODE_DIM + d] = e[d] * inv;
    }
}

// ---------------------------------------------------------------------------
// adj = clip(sym(hd @ we + be), diag=-10).  One block per graph, 256 threads,
// 40KB LDS holds the 100x100 score tile for the symmetrize epilogue.
// ---------------------------------------------------------------------------
__global__ void adj_kernel(const float* __restrict__ hd,
                           const float* __restrict__ we, const float* __restrict__ be,
                           float* __restrict__ out_adj) {
    const int g = blockIdx.x;
    const int tid = threadIdx.x;
    __shared__ float s_hd[HIDDEN];
    __shared__ float s_a[MAX_NODES * MAX_NODES];  // 10000 floats = 40KB

    if (tid < HIDDEN) s_hd[tid] = hd[g * HIDDEN + tid];
    __syncthreads();

    for (int o = tid; o < MAX_NODES * MAX_NODES; o += blockDim.x) {
        float a = be[o];
        for (int k = 0; k < HIDDEN; ++k) a += s_hd[k] * we[k * (MAX_NODES * MAX_NODES) + o];
        s_a[o] = a;
    }
    __syncthreads();

    for (int o = tid; o < MAX_NODES * MAX_NODES; o += blockDim.x) {
        const int i = o / MAX_NODES;
        const int j = o - i * MAX_NODES;
        float v;
        if (i == j) {
            v = -10.f;
        } else {
            v = 0.5f * (s_a[o] + s_a[j * MAX_NODES + i]);
            v = fminf(fmaxf(v, -10.f), 10.f);
        }
        out_adj[(long)g * MAX_NODES * MAX_NODES + o] = v;
    }
}

// ---------------------------------------------------------------------------
extern "C" void kernel_launch(void* const* d_in, const int* in_sizes, int n_in,
                              void* d_out, int out_size, void* d_ws, size_t ws_size,
                              hipStream_t stream) {
    const float* x    = (const float*)d_in[0];
    const int*   edge = (const int*)d_in[1];
    const int*   src  = edge;
    const int*   dst  = edge + N_EDGES;
    const int*   batch = (const int*)d_in[2];
    const float* eps  = (const float*)d_in[3];
    const float* w1a = (const float*)d_in[4],  *b1a = (const float*)d_in[5];
    const float* w1b = (const float*)d_in[6],  *b1b = (const float*)d_in[7];
    const float* w2a = (const float*)d_in[8],  *b2a = (const float*)d_in[9];
    const float* w2b = (const float*)d_in[10], *b2b = (const float*)d_in[11];
    const float* wmu = (const float*)d_in[12], *bmu = (const float*)d_in[13];
    const float* wlv = (const float*)d_in[14], *blv = (const float*)d_in[15];
    const float* wd1 = (const float*)d_in[16], *bd1 = (const float*)d_in[17];
    const float* wd2 = (const float*)d_in[18], *bd2 = (const float*)d_in[19];
    const float* wn  = (const float*)d_in[20], *bn  = (const float*)d_in[21];
    const float* we  = (const float*)d_in[22], *be  = (const float*)d_in[23];

    float* out = (float*)d_out;
    float* out_adj = out;                                        // 2,560,000
    float* out_nf  = out + (long)NUM_GRAPHS * MAX_NODES * MAX_NODES;       // 409,600
    float* out_mu  = out_nf + (long)NUM_GRAPHS * MAX_NODES * NODE_DIM;     // 16,384
    float* out_lv  = out_mu + NUM_GRAPHS * LATENT;                         // 16,384

    float* ws = (float*)d_ws;
    float* agg1   = ws;                      // 800,000
    float* h1     = agg1 + (long)N_NODES * NODE_DIM;   // 6,400,000
    float* agg2   = h1 + (long)N_NODES * HIDDEN;       // 6,400,000
    float* summed = agg2 + (long)N_NODES * HIDDEN;     // 32,768
    float* counts = summed + NUM_GRAPHS * HIDDEN;      // 256
    float* hd     = counts + NUM_GRAPHS;               // 32,768
    float* h2     = h1;  // reuse: h1 dead once agg2 is built

    // ---- GIN layer 1 ----
    hipMemcpyAsync(agg1, x, sizeof(float) * (size_t)N_NODES * NODE_DIM,
                   hipMemcpyDeviceToDevice, stream);
    scatter_add_kernel<NODE_DIM><<<2048, 256, 0, stream>>>(x, src, dst, agg1);
    gin_mlp_kernel<NODE_DIM, 8><<<(N_NODES + 7) / 8, 128, 0, stream>>>(
        agg1, w1a, b1a, w1b, b1b, h1);

    // ---- GIN layer 2 ----
    hipMemcpyAsync(agg2, h1, sizeof(float) * (size_t)N_NODES * HIDDEN,
                   hipMemcpyDeviceToDevice, stream);
    scatter_add_kernel<HIDDEN><<<2048, 256, 0, stream>>>(h1, src, dst, agg2);
    gin_mlp_kernel<HIDDEN, 8><<<(N_NODES + 7) / 8, 128, 0, stream>>>(
        agg2, w2a, b2a, w2b, b2b, h2);

    // ---- mean pool ----
    hipMemsetAsync(summed, 0, sizeof(float) * (NUM_GRAPHS * HIDDEN + NUM_GRAPHS), stream);
    pool_kernel<<<(N_NODES + 127) / 128, 128, 0, stream>>>(h2, batch, summed, counts);

    // ---- heads + reparam + decoder trunk ----
    head_kernel<<<NUM_GRAPHS, 128, 0, stream>>>(summed, counts, eps,
                                                wmu, bmu, wlv, blv,
                                                wd1, bd1, wd2, bd2,
                                                out_mu, out_lv, hd);

    // ---- decoder outputs ----
    nodefeat_kernel<<<NUM_GRAPHS, 128, 0, stream>>>(hd, wn, bn, out_nf);
    adj_kernel<<<NUM_GRAPHS, 256, 0, stream>>>(hd, we, be, out_adj);
}